// Round 7
// baseline (169.666 us; speedup 1.0000x reference)
//
#include <hip/hip_runtime.h>

// ---------------------------------------------------------------------------
// BasicAttention: dwconv3x3 -> pointwise 1x1 (C->3C) -> 4-head attention S=4096
// B=4, C=256, H=W=64, heads=4, d=64. Output f32 [B,C,H,W].
//
//  k_wcvt : w_pw f32 -> bf16, 0.125*log2e folded into q rows
//  k_dw   : depthwise conv -> DWt[b][s][c] bf16 (c-contiguous, via LDS transpose)
//  k_pw   : GEMM -> Q,K,Vt; DWt staged once, 12 o-tiles looped in-block
//  k_attn : flash attention, swapped QK^T (S^T=mfma(K,Q)), in-register softmax
//           (shfl_xor(32) exchanges), defer-max, l via ones-MFMA (MFMA pipe is
//           NOT the bottleneck - r6 lesson), K/V dbuf global_load_lds.
//           grid 512 x 4 waves = 2 independent barrier domains per CU.
// ---------------------------------------------------------------------------

typedef __attribute__((ext_vector_type(8))) __bf16 bf16x8;
typedef __attribute__((ext_vector_type(4))) float f32x4;
typedef __attribute__((ext_vector_type(16))) float f32x16;
typedef __attribute__((ext_vector_type(8))) unsigned short ushort8;
typedef __attribute__((ext_vector_type(4))) unsigned int uint4v;

#define OFF_DW 0ull
#define OFF_WB 8388608ull
#define OFF_Q  8781824ull
#define OFF_K  17170432ull
#define OFF_V  25559040ull

__device__ __forceinline__ unsigned short f2bf(float x) {
  unsigned u = __builtin_bit_cast(unsigned, x);
  u += 0x7fffu + ((u >> 16) & 1u);           // RNE
  return (unsigned short)(u >> 16);
}

__device__ __forceinline__ void gld16(const void* g, void* l) {
  __builtin_amdgcn_global_load_lds((const __attribute__((address_space(1))) void*)g,
                                   (__attribute__((address_space(3))) void*)l, 16, 0, 0);
}

__device__ __forceinline__ unsigned cvtpk(float lo, float hi) {
  unsigned r;
  asm("v_cvt_pk_bf16_f32 %0, %1, %2" : "=v"(r) : "v"(lo), "v"(hi));
  return r;
}

// ---------------- kernel 0: convert w_pw to bf16, fold softmax scale --------
__global__ __launch_bounds__(256) void k_wcvt(const float* __restrict__ wpw,
                                              unsigned short* __restrict__ wbf) {
  int idx = blockIdx.x * 256 + threadIdx.x;
  int o = idx >> 8;
  float v = wpw[idx];
  if (o < 256) v *= 0.18033688011112042f;         // 0.125 * log2(e)
  wbf[idx] = f2bf(v);
}

// ---------------- kernel 1: depthwise 3x3 conv -> DWt[b][s][c] bf16 ---------
__global__ __launch_bounds__(256) void k_dw(const float* __restrict__ x,
                                            const float* __restrict__ wdw,
                                            unsigned short* __restrict__ dwt) {
  __shared__ float tile[64 * 65];
  const int t = threadIdx.x;
  const int h = blockIdx.x;
  const int c0 = blockIdx.y * 64;
  const int b = blockIdx.z;
  const int w = t & 63;
  const int wq = t >> 6;
#pragma unroll
  for (int i = 0; i < 16; ++i) {
    int cl = wq * 16 + i;
    int c = c0 + cl;
    const float* wd = wdw + c * 9;
    const float* xb = x + ((size_t)(b * 256 + c) * 64) * 64;
    float acc = 0.f;
#pragma unroll
    for (int ky = 0; ky < 3; ++ky) {
      int hh = h + ky - 1;
      if ((unsigned)hh < 64u) {
        const float* row = xb + hh * 64;
#pragma unroll
        for (int kx = 0; kx < 3; ++kx) {
          int ww = w + kx - 1;
          if ((unsigned)ww < 64u) acc += row[ww] * wd[ky * 3 + kx];
        }
      }
    }
    tile[w * 65 + cl] = acc;
  }
  __syncthreads();
  int sl = t >> 2, cch = (t & 3) * 16;
  ushort8 p0, p1;
#pragma unroll
  for (int j = 0; j < 8; ++j) p0[j] = f2bf(tile[sl * 65 + cch + j]);
#pragma unroll
  for (int j = 0; j < 8; ++j) p1[j] = f2bf(tile[sl * 65 + cch + 8 + j]);
  unsigned short* dst = dwt + ((size_t)(b * 4096 + h * 64 + sl)) * 256 + c0 + cch;
  *(ushort8*)dst = p0;
  *(ushort8*)(dst + 8) = p1;
}

// ---------------- kernel 2: pointwise GEMM -> Q,K,Vt ------------------------
// grid (64 s-tiles, 4 b), 256 thr. DWt tile staged ONCE; 12 o-tiles looped.
__global__ __launch_bounds__(256) void k_pw(const unsigned short* __restrict__ dwt,
                                            const unsigned short* __restrict__ wbf,
                                            unsigned short* __restrict__ q,
                                            unsigned short* __restrict__ k,
                                            unsigned short* __restrict__ v) {
  __shared__ __align__(16) unsigned char smem[82176];
  const int t = threadIdx.x;
  const int lane = t & 63, wv = t >> 6;
  const int s0 = blockIdx.x * 64;
  const int b = blockIdx.y;
  const int vb = ((lane >> 5) << 9) + (((lane & 31) ^ (lane >> 5)) << 4);
  const char* dsrc = (const char*)dwt + ((size_t)(b * 4096 + s0)) * 512;
#pragma unroll
  for (int i = 0; i < 8; ++i) {
    int I = wv * 8 + i;
    int u = ((2 * i) & 7) << 4;
    gld16(dsrc + (size_t)I * 1024 + (vb ^ u), smem + 32768 + I * 1024);
    gld16((const char*)wbf + (size_t)I * 1024 + (vb ^ u), smem + I * 1024);  // W(0)
  }
  asm volatile("s_waitcnt vmcnt(0)" ::: "memory");
  __syncthreads();

  const int c15 = lane & 15, g = lane >> 4;
  const int orow = wv * 16 + c15;

#pragma unroll 1
  for (int yy = 0; yy < 12; ++yy) {
    f32x4 acc[4] = {{0,0,0,0},{0,0,0,0},{0,0,0,0},{0,0,0,0}};
#pragma unroll
    for (int kc = 0; kc < 8; ++kc) {
      bf16x8 a = *(const bf16x8*)(smem + orow * 512 + (((kc * 4 + g) ^ (orow & 7)) << 4));
#pragma unroll
      for (int nt = 0; nt < 4; ++nt) {
        int srow = nt * 16 + c15;
        bf16x8 bb = *(const bf16x8*)(smem + 32768 + srow * 512 + (((kc * 4 + g) ^ (srow & 7)) << 4));
        acc[nt] = __builtin_amdgcn_mfma_f32_16x16x32_bf16(a, bb, acc[nt], 0, 0, 0);
      }
    }

    const int type = yy >> 2, head = yy & 3;
    const size_t bh = (size_t)(b * 4 + head);
    if (type == 2) {
#pragma unroll
      for (int nt = 0; nt < 4; ++nt)
#pragma unroll
        for (int r = 0; r < 4; ++r) {
          int d = wv * 16 + g * 4 + r;
          int sg = s0 + nt * 16 + c15;
          v[(bh * 64 + d) * 4096 + sg] = f2bf(acc[nt][r]);
        }
    } else {
      float* ol = (float*)(smem + 65536);
#pragma unroll
      for (int nt = 0; nt < 4; ++nt)
#pragma unroll
        for (int r = 0; r < 4; ++r)
          ol[(nt * 16 + c15) * 65 + (wv * 16 + g * 4 + r)] = acc[nt][r];
      __syncthreads();
      unsigned short* dst0 = (type == 0) ? q : k;
      int sl = t >> 2, dch = (t & 3) * 16;
      ushort8 p0, p1;
#pragma unroll
      for (int j = 0; j < 8; ++j) p0[j] = f2bf(ol[sl * 65 + dch + j]);
#pragma unroll
      for (int j = 0; j < 8; ++j) p1[j] = f2bf(ol[sl * 65 + dch + 8 + j]);
      unsigned short* dst = dst0 + (bh * 4096 + s0 + sl) * 64 + dch;
      *(ushort8*)dst = p0;
      *(ushort8*)(dst + 8) = p1;
    }

    __syncthreads();          // all waves done with W(yy) + ol reads
    if (yy < 11) {
#pragma unroll
      for (int i = 0; i < 8; ++i) {
        int I = wv * 8 + i;
        int u = ((2 * i) & 7) << 4;
        gld16((const char*)wbf + (size_t)(yy + 1) * 32768 + (size_t)I * 1024 + (vb ^ u),
              smem + I * 1024);
      }
      asm volatile("s_waitcnt vmcnt(0)" ::: "memory");
      __syncthreads();        // W(yy+1) visible
    }
  }
}

// ---------------- kernel 3: flash attention (swapped QK^T, in-reg softmax) --
// grid 512 = (xcd-grouped bh, 32 s-tiles of 128); 4 waves x 32 q-rows;
// KVBLK=64 dbuf; 48KB LDS -> 2 blocks/CU = 2 independent barrier domains.
__global__ __launch_bounds__(256) void k_attn(const unsigned short* __restrict__ qg,
                                              const unsigned short* __restrict__ kg,
                                              const unsigned short* __restrict__ vg,
                                              float* __restrict__ out) {
  __shared__ __align__(16) unsigned char smem[49152];   // Q 16K | K/V dbuf 32K
  const int t = threadIdx.x;
  const int lane = t & 63, wv = t >> 6;
  const int l31 = lane & 31, hi = lane >> 5;

  const int blk = blockIdx.x;
  const int xcd = blk & 7, idx = blk >> 3;
  const int bh = xcd * 2 + (idx & 1);            // same-bh blocks share an XCD L2
  const int s0 = (idx >> 1) * 128;

  const char* qsrc = (const char*)qg + (size_t)bh * 524288 + (size_t)s0 * 128;
  const char* ksrc = (const char*)kg + (size_t)bh * 524288;
  const char* vsrc = (const char*)vg + (size_t)bh * 524288;
  // staging swizzle: 8 rows of 128B per gld16-wave; slot = chunk ^ (row&7)
  const int vQK = ((lane >> 3) << 7) + (((lane & 7) ^ (lane >> 3)) << 4);
  const int vV  = ((lane >> 3) << 13) + (((lane & 7) ^ (lane >> 3)) << 4);

  // prologue: stage Q (16KB) + K/V tile 0 (4 waves: 4 Q parts + 2K + 2V each)
#pragma unroll
  for (int i = 0; i < 4; ++i) {
    int I = wv * 4 + i;
    gld16(qsrc + (size_t)I * 1024 + vQK, smem + I * 1024);
  }
  {
    int I0 = wv * 2;
#pragma unroll
    for (int i = 0; i < 2; ++i) {
      int I = I0 + i;
      gld16(ksrc + (size_t)I * 1024 + vQK, smem + 16384 + I * 1024);
      gld16(vsrc + (size_t)I * 65536 + vV, smem + 24576 + I * 1024);
    }
  }
  asm volatile("s_waitcnt vmcnt(0)" ::: "memory");
  __syncthreads();

  // Q fragments (B-operand: lane holds Q[s=wv*32+l31][d = 16*ks + 8*hi + j])
  bf16x8 qf[4];
  {
    int row = wv * 32 + l31;
#pragma unroll
    for (int ks = 0; ks < 4; ++ks)
      qf[ks] = *(const bf16x8*)(smem + row * 128 + (((ks * 2 + hi) ^ (row & 7)) << 4));
  }

  f32x16 O0, O1, lacc;
#pragma unroll
  for (int r = 0; r < 16; ++r) { O0[r] = 0.f; O1[r] = 0.f; lacc[r] = 0.f; }
  float m = -1e30f;
  float* sflp = (float*)(smem + wv * 4096);       // wave-private (old Q rows)

  uint4v onesu;
  onesu[0] = onesu[1] = onesu[2] = onesu[3] = 0x3F803F80u;  // bf16 1.0 x8
  const bf16x8 onesb = __builtin_bit_cast(bf16x8, onesu);

#pragma unroll 2
  for (int it = 0; it < 64; ++it) {
    const unsigned char* kb = smem + 16384 + (it & 1) * 16384;
    const unsigned char* vbuf = kb + 8192;
    unsigned char* nb = smem + 16384 + ((it + 1) & 1) * 16384;
    if (it < 63) {                                // stage next tile (4 gld16/wave)
      int I0 = wv * 2;
#pragma unroll
      for (int i = 0; i < 2; ++i) {
        int I = I0 + i;
        gld16(ksrc + (size_t)(it + 1) * 8192 + (size_t)I * 1024 + vQK, nb + I * 1024);
        gld16(vsrc + (size_t)(it + 1) * 128 + (size_t)I * 65536 + vV, nb + 8192 + I * 1024);
      }
    }

    // QK^T swapped: S^T[t][s], col=lane&31 = s (q-row lane-local).
    // sc reg r holds t = (r&3) + 8*(r>>2) + 4*hi (within 32-block).
    f32x16 sc0, sc1;
#pragma unroll
    for (int r = 0; r < 16; ++r) { sc0[r] = 0.f; sc1[r] = 0.f; }
    __builtin_amdgcn_s_setprio(1);
#pragma unroll
    for (int ks = 0; ks < 4; ++ks) {
      int sw = ((ks * 2 + hi) ^ (l31 & 7)) << 4;
      bf16x8 kf0 = *(const bf16x8*)(kb + l31 * 128 + sw);
      sc0 = __builtin_amdgcn_mfma_f32_32x32x16_bf16(kf0, qf[ks], sc0, 0, 0, 0);
      bf16x8 kf1 = *(const bf16x8*)(kb + (32 + l31) * 128 + sw);
      sc1 = __builtin_amdgcn_mfma_f32_32x32x16_bf16(kf1, qf[ks], sc1, 0, 0, 0);
    }
    __builtin_amdgcn_s_setprio(0);

    // row max: depth-5 tree + 1 cross-half shfl_xor
    float mx[16];
#pragma unroll
    for (int r = 0; r < 16; ++r) mx[r] = fmaxf(sc0[r], sc1[r]);
#pragma unroll
    for (int st = 8; st > 0; st >>= 1)
#pragma unroll
      for (int r2 = 0; r2 < 8; ++r2)
        if (r2 < st) mx[r2] = fmaxf(mx[r2], mx[r2 + st]);
    float pmax = fmaxf(mx[0], __shfl_xor(mx[0], 32));

    // defer-max (THR=8 in log2 domain): rescale only when max grows
    if (__any(pmax > m + 8.0f)) {
      float mn = fmaxf(m, pmax);
      float sf = __builtin_amdgcn_exp2f(m - mn);
      m = mn;
      sflp[l31] = sf;                              // both halves write same value
      f32x4 s4[4];
#pragma unroll
      for (int g4 = 0; g4 < 4; ++g4) s4[g4] = *(const f32x4*)(sflp + g4 * 8 + hi * 4);
#pragma unroll
      for (int r = 0; r < 16; ++r) {
        float f = s4[r >> 2][r & 3];               // sf for O-row s=(r&3)+8(r>>2)+4hi
        O0[r] *= f; O1[r] *= f; lacc[r] *= f;
      }
    }

#pragma unroll
    for (int r = 0; r < 16; ++r) {
      sc0[r] = __builtin_amdgcn_exp2f(sc0[r] - m);
      sc1[r] = __builtin_amdgcn_exp2f(sc1[r] - m);
    }

    // P -> PV A-fragments in-register, 2 bpermutes per 16-t slice:
    // pre-select what the partner needs, exchange once, post-select.
    //   hi=0 needs [c0, c1, partner.c0, partner.c1]  (t 0..7)
    //   hi=1 needs [partner.c2, partner.c3, c2, c3]  (t 8..15)
    uint4v paw[4];
    {
      auto mkchunk = [&](float p0, float p1, float p2, float p3,
                         float p4, float p5, float p6, float p7) -> uint4v {
        unsigned c0 = cvtpk(p0, p1), c1 = cvtpk(p2, p3);
        unsigned c2 = cvtpk(p4, p5), c3 = cvtpk(p6, p7);
        unsigned x0 = hi ? c0 : c2, x1 = hi ? c1 : c3;   // give partner its need
        unsigned r0 = (unsigned)__shfl_xor((int)x0, 32);
        unsigned r1 = (unsigned)__shfl_xor((int)x1, 32);
        uint4v w;
        w[0] = hi ? r0 : c0;
        w[1] = hi ? r1 : c1;
        w[2] = hi ? c2 : r0;
        w[3] = hi ? c3 : r1;
        return w;
      };
      paw[0] = mkchunk(sc0[0], sc0[1], sc0[2], sc0[3], sc0[4], sc0[5], sc0[6], sc0[7]);
      paw[1] = mkchunk(sc0[8], sc0[9], sc0[10], sc0[11], sc0[12], sc0[13], sc0[14], sc0[15]);
      paw[2] = mkchunk(sc1[0], sc1[1], sc1[2], sc1[3], sc1[4], sc1[5], sc1[6], sc1[7]);
      paw[3] = mkchunk(sc1[8], sc1[9], sc1[10], sc1[11], sc1[12], sc1[13], sc1[14], sc1[15]);
    }

    // l via ones-MFMA (lands in O layout; MFMA pipe has headroom) + PV
    __builtin_amdgcn_s_setprio(1);
#pragma unroll
    for (int ks = 0; ks < 4; ++ks) {
      bf16x8 pa = __builtin_bit_cast(bf16x8, paw[ks]);
      lacc = __builtin_amdgcn_mfma_f32_32x32x16_bf16(pa, onesb, lacc, 0, 0, 0);
      int sw = ((ks * 2 + hi) ^ (l31 & 7)) << 4;
      bf16x8 v0 = *(const bf16x8*)(vbuf + l31 * 128 + sw);
      O0 = __builtin_amdgcn_mfma_f32_32x32x16_bf16(pa, v0, O0, 0, 0, 0);
      bf16x8 v1 = *(const bf16x8*)(vbuf + (32 + l31) * 128 + sw);
      O1 = __builtin_amdgcn_mfma_f32_32x32x16_bf16(pa, v1, O1, 0, 0, 0);
    }
    __builtin_amdgcn_s_setprio(0);

    asm volatile("s_waitcnt vmcnt(0)" ::: "memory");
    __syncthreads();
  }

  // epilogue: normalize (lacc already per-O-row), transpose via per-wave LDS
  float rn[16];
#pragma unroll
  for (int r = 0; r < 16; ++r) rn[r] = 1.0f / lacc[r];
  float* ep = (float*)(smem + wv * 4608);          // [32 d][36 f32] per wave
  const size_t outbase = (size_t)bh * 262144 + (size_t)(s0 + wv * 32);
#pragma unroll
  for (int dt = 0; dt < 2; ++dt) {
    const f32x16& O = dt ? O1 : O0;
#pragma unroll
    for (int g4 = 0; g4 < 4; ++g4) {
      f32x4 w;
      w[0] = O[4 * g4 + 0] * rn[4 * g4 + 0];
      w[1] = O[4 * g4 + 1] * rn[4 * g4 + 1];
      w[2] = O[4 * g4 + 2] * rn[4 * g4 + 2];
      w[3] = O[4 * g4 + 3] * rn[4 * g4 + 3];
      *(f32x4*)(ep + l31 * 36 + g4 * 8 + hi * 4) = w;   // [d=l31][s_local]
    }
#pragma unroll
    for (int j = 0; j < 4; ++j) {
      int idx2 = j * 64 + lane;
      int d = idx2 >> 3, s4c = idx2 & 7;
      f32x4 vv = *(const f32x4*)(ep + d * 36 + s4c * 4);
      *(f32x4*)(out + outbase + (size_t)(dt * 32 + d) * 4096 + s4c * 4) = vv;
    }
  }
}

// ---------------------------------------------------------------------------
extern "C" void kernel_launch(void* const* d_in, const int* in_sizes, int n_in,
                              void* d_out, int out_size, void* d_ws, size_t ws_size,
                              hipStream_t stream) {
  const float* x = (const float*)d_in[0];
  const float* wdw = (const float*)d_in[1];
  const float* wpw = (const float*)d_in[2];
  float* out = (float*)d_out;
  char* ws = (char*)d_ws;
  unsigned short* dwt = (unsigned short*)(ws + OFF_DW);
  unsigned short* wbf = (unsigned short*)(ws + OFF_WB);
  unsigned short* q = (unsigned short*)(ws + OFF_Q);
  unsigned short* k = (unsigned short*)(ws + OFF_K);
  unsigned short* v = (unsigned short*)(ws + OFF_V);

  k_wcvt<<<dim3(768), dim3(256), 0, stream>>>(wpw, wbf);
  k_dw<<<dim3(64, 4, 4), dim3(256), 0, stream>>>(x, wdw, dwt);
  k_pw<<<dim3(64, 4), dim3(256), 0, stream>>>(dwt, wbf, q, k, v);
  k_attn<<<dim3(512), dim3(256), 0, stream>>>(q, k, v, out);
}

// Round 8
// 160.504 us; speedup vs baseline: 1.0571x; 1.0571x over previous
//
#include <hip/hip_runtime.h>

// ---------------------------------------------------------------------------
// BasicAttention: dwconv3x3 -> pointwise 1x1 (C->3C) -> 4-head attention S=4096
// B=4, C=256, H=W=64, heads=4, d=64. Output f32 [B,C,H,W].
//
//  k_wcvt : w_pw f32 -> bf16, 0.125*log2e folded into q rows
//  k_dw   : depthwise conv -> DWt[b][s][c] bf16
//  k_pw   : GEMM -> Q,K,Vt; DWt staged once, 12 o-tiles looped in-block
//  k_attn : flash attention, swapped QK^T, in-register softmax, defer-max,
//           l via ones-MFMA. NEW (r8): 4-buffer KV ring staged 2 tiles ahead,
//           counted s_waitcnt vmcnt(2) + raw s_barrier per tile (no vmem
//           drain at barriers - T4), unroll 4, max3 row-max tree.
//           grid 256 x 512thr (single-staging r5 skeleton, its best: 113us).
// ---------------------------------------------------------------------------

typedef __attribute__((ext_vector_type(8))) __bf16 bf16x8;
typedef __attribute__((ext_vector_type(4))) float f32x4;
typedef __attribute__((ext_vector_type(16))) float f32x16;
typedef __attribute__((ext_vector_type(8))) unsigned short ushort8;
typedef __attribute__((ext_vector_type(4))) unsigned int uint4v;

#define OFF_DW 0ull
#define OFF_WB 8388608ull
#define OFF_Q  8781824ull
#define OFF_K  17170432ull
#define OFF_V  25559040ull

__device__ __forceinline__ unsigned short f2bf(float x) {
  unsigned u = __builtin_bit_cast(unsigned, x);
  u += 0x7fffu + ((u >> 16) & 1u);           // RNE
  return (unsigned short)(u >> 16);
}

__device__ __forceinline__ void gld16(const void* g, void* l) {
  __builtin_amdgcn_global_load_lds((const __attribute__((address_space(1))) void*)g,
                                   (__attribute__((address_space(3))) void*)l, 16, 0, 0);
}

__device__ __forceinline__ unsigned cvtpk(float lo, float hi) {
  unsigned r;
  asm("v_cvt_pk_bf16_f32 %0, %1, %2" : "=v"(r) : "v"(lo), "v"(hi));
  return r;
}

// ---------------- kernel 0: convert w_pw to bf16, fold softmax scale --------
__global__ __launch_bounds__(256) void k_wcvt(const float* __restrict__ wpw,
                                              unsigned short* __restrict__ wbf) {
  int idx = blockIdx.x * 256 + threadIdx.x;
  int o = idx >> 8;
  float v = wpw[idx];
  if (o < 256) v *= 0.18033688011112042f;         // 0.125 * log2(e)
  wbf[idx] = f2bf(v);
}

// ---------------- kernel 1: depthwise 3x3 conv -> DWt[b][s][c] bf16 ---------
__global__ __launch_bounds__(256) void k_dw(const float* __restrict__ x,
                                            const float* __restrict__ wdw,
                                            unsigned short* __restrict__ dwt) {
  __shared__ float tile[64 * 65];
  const int t = threadIdx.x;
  const int h = blockIdx.x;
  const int c0 = blockIdx.y * 64;
  const int b = blockIdx.z;
  const int w = t & 63;
  const int wq = t >> 6;
#pragma unroll
  for (int i = 0; i < 16; ++i) {
    int cl = wq * 16 + i;
    int c = c0 + cl;
    const float* wd = wdw + c * 9;
    const float* xb = x + ((size_t)(b * 256 + c) * 64) * 64;
    float acc = 0.f;
#pragma unroll
    for (int ky = 0; ky < 3; ++ky) {
      int hh = h + ky - 1;
      if ((unsigned)hh < 64u) {
        const float* row = xb + hh * 64;
#pragma unroll
        for (int kx = 0; kx < 3; ++kx) {
          int ww = w + kx - 1;
          if ((unsigned)ww < 64u) acc += row[ww] * wd[ky * 3 + kx];
        }
      }
    }
    tile[w * 65 + cl] = acc;
  }
  __syncthreads();
  int sl = t >> 2, cch = (t & 3) * 16;
  ushort8 p0, p1;
#pragma unroll
  for (int j = 0; j < 8; ++j) p0[j] = f2bf(tile[sl * 65 + cch + j]);
#pragma unroll
  for (int j = 0; j < 8; ++j) p1[j] = f2bf(tile[sl * 65 + cch + 8 + j]);
  unsigned short* dst = dwt + ((size_t)(b * 4096 + h * 64 + sl)) * 256 + c0 + cch;
  *(ushort8*)dst = p0;
  *(ushort8*)(dst + 8) = p1;
}

// ---------------- kernel 2: pointwise GEMM -> Q,K,Vt ------------------------
__global__ __launch_bounds__(256) void k_pw(const unsigned short* __restrict__ dwt,
                                            const unsigned short* __restrict__ wbf,
                                            unsigned short* __restrict__ q,
                                            unsigned short* __restrict__ k,
                                            unsigned short* __restrict__ v) {
  __shared__ __align__(16) unsigned char smem[82176];
  const int t = threadIdx.x;
  const int lane = t & 63, wv = t >> 6;
  const int s0 = blockIdx.x * 64;
  const int b = blockIdx.y;
  const int vb = ((lane >> 5) << 9) + (((lane & 31) ^ (lane >> 5)) << 4);
  const char* dsrc = (const char*)dwt + ((size_t)(b * 4096 + s0)) * 512;
#pragma unroll
  for (int i = 0; i < 8; ++i) {
    int I = wv * 8 + i;
    int u = ((2 * i) & 7) << 4;
    gld16(dsrc + (size_t)I * 1024 + (vb ^ u), smem + 32768 + I * 1024);
    gld16((const char*)wbf + (size_t)I * 1024 + (vb ^ u), smem + I * 1024);  // W(0)
  }
  asm volatile("s_waitcnt vmcnt(0)" ::: "memory");
  __syncthreads();

  const int c15 = lane & 15, g = lane >> 4;
  const int orow = wv * 16 + c15;

#pragma unroll 1
  for (int yy = 0; yy < 12; ++yy) {
    f32x4 acc[4] = {{0,0,0,0},{0,0,0,0},{0,0,0,0},{0,0,0,0}};
#pragma unroll
    for (int kc = 0; kc < 8; ++kc) {
      bf16x8 a = *(const bf16x8*)(smem + orow * 512 + (((kc * 4 + g) ^ (orow & 7)) << 4));
#pragma unroll
      for (int nt = 0; nt < 4; ++nt) {
        int srow = nt * 16 + c15;
        bf16x8 bb = *(const bf16x8*)(smem + 32768 + srow * 512 + (((kc * 4 + g) ^ (srow & 7)) << 4));
        acc[nt] = __builtin_amdgcn_mfma_f32_16x16x32_bf16(a, bb, acc[nt], 0, 0, 0);
      }
    }

    const int type = yy >> 2, head = yy & 3;
    const size_t bh = (size_t)(b * 4 + head);
    if (type == 2) {
#pragma unroll
      for (int nt = 0; nt < 4; ++nt)
#pragma unroll
        for (int r = 0; r < 4; ++r) {
          int d = wv * 16 + g * 4 + r;
          int sg = s0 + nt * 16 + c15;
          v[(bh * 64 + d) * 4096 + sg] = f2bf(acc[nt][r]);
        }
    } else {
      float* ol = (float*)(smem + 65536);
#pragma unroll
      for (int nt = 0; nt < 4; ++nt)
#pragma unroll
        for (int r = 0; r < 4; ++r)
          ol[(nt * 16 + c15) * 65 + (wv * 16 + g * 4 + r)] = acc[nt][r];
      __syncthreads();
      unsigned short* dst0 = (type == 0) ? q : k;
      int sl = t >> 2, dch = (t & 3) * 16;
      ushort8 p0, p1;
#pragma unroll
      for (int j = 0; j < 8; ++j) p0[j] = f2bf(ol[sl * 65 + dch + j]);
#pragma unroll
      for (int j = 0; j < 8; ++j) p1[j] = f2bf(ol[sl * 65 + dch + 8 + j]);
      unsigned short* dst = dst0 + (bh * 4096 + s0 + sl) * 64 + dch;
      *(ushort8*)dst = p0;
      *(ushort8*)(dst + 8) = p1;
    }

    __syncthreads();          // all waves done with W(yy) + ol reads
    if (yy < 11) {
#pragma unroll
      for (int i = 0; i < 8; ++i) {
        int I = wv * 8 + i;
        int u = ((2 * i) & 7) << 4;
        gld16((const char*)wbf + (size_t)(yy + 1) * 32768 + (size_t)I * 1024 + (vb ^ u),
              smem + I * 1024);
      }
      asm volatile("s_waitcnt vmcnt(0)" ::: "memory");
      __syncthreads();        // W(yy+1) visible
    }
  }
}

// ---------------- kernel 3: flash attention -------------------------------
// grid 256 = (xcd-grouped bh, 16 s-tiles of 256); 8 waves x 32 q-rows.
// LDS 96KB: Q 32K | KV ring 4 x 16K. Stage 2 tiles ahead; per tile:
// {issue stage(it+2); compute(it); vmcnt(2) [certifies it+1]; s_barrier}.
__global__ __launch_bounds__(512) void k_attn(const unsigned short* __restrict__ qg,
                                              const unsigned short* __restrict__ kg,
                                              const unsigned short* __restrict__ vg,
                                              float* __restrict__ out) {
  __shared__ __align__(16) unsigned char smem[98304];
  const int t = threadIdx.x;
  const int lane = t & 63, wv = t >> 6;
  const int l31 = lane & 31, hi = lane >> 5;

  const int blk = blockIdx.x;
  const int xcd = blk & 7, idx = blk >> 3;
  const int bh = xcd * 2 + (idx & 1);            // same-bh blocks share an XCD L2
  const int s0 = (idx >> 1) * 256;

  const char* qsrc = (const char*)qg + (size_t)bh * 524288 + (size_t)s0 * 128;
  const char* ksrc = (const char*)kg + (size_t)bh * 524288;
  const char* vsrc = (const char*)vg + (size_t)bh * 524288;
  // staging swizzle: 8 rows of 128B per gld16-wave; slot = chunk ^ (row&7)
  const int vQK = ((lane >> 3) << 7) + (((lane & 7) ^ (lane >> 3)) << 4);
  const int vV  = ((lane >> 3) << 13) + (((lane & 7) ^ (lane >> 3)) << 4);

  // prologue: stage Q (own wave's 32 rows) + K/V tiles 0,1 into ring bufs 0,1
#pragma unroll
  for (int i = 0; i < 4; ++i) {
    int I = wv * 4 + i;
    gld16(qsrc + (size_t)I * 1024 + vQK, smem + I * 1024);
  }
#pragma unroll
  for (int tt = 0; tt < 2; ++tt) {
    unsigned char* tb = smem + 32768 + tt * 16384;
    if (wv < 4) {
#pragma unroll
      for (int i = 0; i < 2; ++i) {
        int I = wv * 2 + i;
        gld16(ksrc + (size_t)tt * 8192 + (size_t)I * 1024 + vQK, tb + I * 1024);
      }
    } else {
#pragma unroll
      for (int i = 0; i < 2; ++i) {
        int I = (wv - 4) * 2 + i;
        gld16(vsrc + (size_t)tt * 128 + (size_t)I * 65536 + vV, tb + 8192 + I * 1024);
      }
    }
  }
  // wait Q(4)+tile0(2) landed (tile1's 2 remain in flight), then barrier
  asm volatile("s_waitcnt vmcnt(2)" ::: "memory");
  __builtin_amdgcn_s_barrier();
  asm volatile("" ::: "memory");

  // Q fragments (B-operand: lane holds Q[s=wv*32+l31][d = 16*ks + 8*hi + j])
  bf16x8 qf[4];
  {
    int row = wv * 32 + l31;
#pragma unroll
    for (int ks = 0; ks < 4; ++ks)
      qf[ks] = *(const bf16x8*)(smem + row * 128 + (((ks * 2 + hi) ^ (row & 7)) << 4));
  }

  f32x16 O0, O1, lacc;
#pragma unroll
  for (int r = 0; r < 16; ++r) { O0[r] = 0.f; O1[r] = 0.f; lacc[r] = 0.f; }
  float m = -1e30f;
  float* sflp = (float*)(smem + wv * 4096);       // wave-private (dead Q rows)

  uint4v onesu;
  onesu[0] = onesu[1] = onesu[2] = onesu[3] = 0x3F803F80u;  // bf16 1.0 x8
  const bf16x8 onesb = __builtin_bit_cast(bf16x8, onesu);

#pragma unroll 4
  for (int it = 0; it < 64; ++it) {
    const unsigned char* kb = smem + 32768 + (it & 3) * 16384;   // compile-time
    const unsigned char* vbuf = kb + 8192;
    if (it < 62) {                                // stage it+2 into ring
      unsigned char* nb = smem + 32768 + ((it + 2) & 3) * 16384;
      if (wv < 4) {
#pragma unroll
        for (int i = 0; i < 2; ++i) {
          int I = wv * 2 + i;
          gld16(ksrc + (size_t)(it + 2) * 8192 + (size_t)I * 1024 + vQK, nb + I * 1024);
        }
      } else {
#pragma unroll
        for (int i = 0; i < 2; ++i) {
          int I = (wv - 4) * 2 + i;
          gld16(vsrc + (size_t)(it + 2) * 128 + (size_t)I * 65536 + vV, nb + 8192 + I * 1024);
        }
      }
    }

    // QK^T swapped: S^T[t][s], col=lane&31 = s (q-row lane-local).
    f32x16 sc0, sc1;
#pragma unroll
    for (int r = 0; r < 16; ++r) { sc0[r] = 0.f; sc1[r] = 0.f; }
    __builtin_amdgcn_s_setprio(1);
#pragma unroll
    for (int ks = 0; ks < 4; ++ks) {
      int sw = ((ks * 2 + hi) ^ (l31 & 7)) << 4;
      bf16x8 kf0 = *(const bf16x8*)(kb + l31 * 128 + sw);
      sc0 = __builtin_amdgcn_mfma_f32_32x32x16_bf16(kf0, qf[ks], sc0, 0, 0, 0);
      bf16x8 kf1 = *(const bf16x8*)(kb + (32 + l31) * 128 + sw);
      sc1 = __builtin_amdgcn_mfma_f32_32x32x16_bf16(kf1, qf[ks], sc1, 0, 0, 0);
    }
    __builtin_amdgcn_s_setprio(0);

    // row max: max3 tree (clang fuses nested fmaxf) + 1 cross-half shfl
    float m0 = fmaxf(fmaxf(sc0[0], sc0[1]), sc0[2]);
    float m1 = fmaxf(fmaxf(sc0[3], sc0[4]), sc0[5]);
    float m2 = fmaxf(fmaxf(sc0[6], sc0[7]), sc0[8]);
    float m3 = fmaxf(fmaxf(sc0[9], sc0[10]), sc0[11]);
    float m4 = fmaxf(fmaxf(sc0[12], sc0[13]), sc0[14]);
    float m5 = fmaxf(fmaxf(sc0[15], sc1[0]), sc1[1]);
    float m6 = fmaxf(fmaxf(sc1[2], sc1[3]), sc1[4]);
    float m7 = fmaxf(fmaxf(sc1[5], sc1[6]), sc1[7]);
    float m8 = fmaxf(fmaxf(sc1[8], sc1[9]), sc1[10]);
    float m9 = fmaxf(fmaxf(sc1[11], sc1[12]), sc1[13]);
    float ma = fmaxf(sc1[14], sc1[15]);
    m0 = fmaxf(fmaxf(m0, m1), m2);
    m3 = fmaxf(fmaxf(m3, m4), m5);
    m6 = fmaxf(fmaxf(m6, m7), m8);
    m9 = fmaxf(m9, ma);
    float pmax = fmaxf(fmaxf(m0, m3), fmaxf(m6, m9));
    pmax = fmaxf(pmax, __shfl_xor(pmax, 32));

    // defer-max (THR=8 in log2 domain): rescale only when max grows
    if (__any(pmax > m + 8.0f)) {
      float mn = fmaxf(m, pmax);
      float sf = __builtin_amdgcn_exp2f(m - mn);
      m = mn;
      sflp[l31] = sf;                              // both halves write same value
      f32x4 s4[4];
#pragma unroll
      for (int g4 = 0; g4 < 4; ++g4) s4[g4] = *(const f32x4*)(sflp + g4 * 8 + hi * 4);
#pragma unroll
      for (int r = 0; r < 16; ++r) {
        float f = s4[r >> 2][r & 3];               // sf for O-row s=(r&3)+8(r>>2)+4hi
        O0[r] *= f; O1[r] *= f; lacc[r] *= f;
      }
    }

#pragma unroll
    for (int r = 0; r < 16; ++r) {
      sc0[r] = __builtin_amdgcn_exp2f(sc0[r] - m);
      sc1[r] = __builtin_amdgcn_exp2f(sc1[r] - m);
    }

    // P -> PV A-fragments, 2 shfl_xor(32) per 16-t slice (pre-select)
    uint4v paw[4];
    {
      auto mkchunk = [&](float p0, float p1, float p2, float p3,
                         float p4, float p5, float p6, float p7) -> uint4v {
        unsigned c0 = cvtpk(p0, p1), c1 = cvtpk(p2, p3);
        unsigned c2 = cvtpk(p4, p5), c3 = cvtpk(p6, p7);
        unsigned x0 = hi ? c0 : c2, x1 = hi ? c1 : c3;   // give partner its need
        unsigned r0 = (unsigned)__shfl_xor((int)x0, 32);
        unsigned r1 = (unsigned)__shfl_xor((int)x1, 32);
        uint4v w;
        w[0] = hi ? r0 : c0;
        w[1] = hi ? r1 : c1;
        w[2] = hi ? c2 : r0;
        w[3] = hi ? c3 : r1;
        return w;
      };
      paw[0] = mkchunk(sc0[0], sc0[1], sc0[2], sc0[3], sc0[4], sc0[5], sc0[6], sc0[7]);
      paw[1] = mkchunk(sc0[8], sc0[9], sc0[10], sc0[11], sc0[12], sc0[13], sc0[14], sc0[15]);
      paw[2] = mkchunk(sc1[0], sc1[1], sc1[2], sc1[3], sc1[4], sc1[5], sc1[6], sc1[7]);
      paw[3] = mkchunk(sc1[8], sc1[9], sc1[10], sc1[11], sc1[12], sc1[13], sc1[14], sc1[15]);
    }

    // l via ones-MFMA (MFMA pipe has headroom) + PV
    __builtin_amdgcn_s_setprio(1);
#pragma unroll
    for (int ks = 0; ks < 4; ++ks) {
      bf16x8 pa = __builtin_bit_cast(bf16x8, paw[ks]);
      lacc = __builtin_amdgcn_mfma_f32_32x32x16_bf16(pa, onesb, lacc, 0, 0, 0);
      int sw = ((ks * 2 + hi) ^ (l31 & 7)) << 4;
      bf16x8 v0 = *(const bf16x8*)(vbuf + l31 * 128 + sw);
      O0 = __builtin_amdgcn_mfma_f32_32x32x16_bf16(pa, v0, O0, 0, 0, 0);
      bf16x8 v1 = *(const bf16x8*)(vbuf + (32 + l31) * 128 + sw);
      O1 = __builtin_amdgcn_mfma_f32_32x32x16_bf16(pa, v1, O1, 0, 0, 0);
    }
    __builtin_amdgcn_s_setprio(0);

    // certify tile it+1 for everyone (stage(it+2) stays in flight), barrier
    if (it < 62) {
      asm volatile("s_waitcnt vmcnt(2)" ::: "memory");
    } else {
      asm volatile("s_waitcnt vmcnt(0)" ::: "memory");
    }
    __builtin_amdgcn_s_barrier();
    asm volatile("" ::: "memory");
  }

  // epilogue: normalize (lacc already per-O-row), transpose via per-wave LDS
  float rn[16];
#pragma unroll
  for (int r = 0; r < 16; ++r) rn[r] = 1.0f / lacc[r];
  float* ep = (float*)(smem + wv * 4608);          // [32 d][36 f32] per wave
  const size_t outbase = (size_t)bh * 262144 + (size_t)(s0 + wv * 32);
#pragma unroll
  for (int dt = 0; dt < 2; ++dt) {
    const f32x16& O = dt ? O1 : O0;
#pragma unroll
    for (int g4 = 0; g4 < 4; ++g4) {
      f32x4 w;
      w[0] = O[4 * g4 + 0] * rn[4 * g4 + 0];
      w[1] = O[4 * g4 + 1] * rn[4 * g4 + 1];
      w[2] = O[4 * g4 + 2] * rn[4 * g4 + 2];
      w[3] = O[4 * g4 + 3] * rn[4 * g4 + 3];
      *(f32x4*)(ep + l31 * 36 + g4 * 8 + hi * 4) = w;   // [d=l31][s_local]
    }
#pragma unroll
    for (int j = 0; j < 4; ++j) {
      int idx2 = j * 64 + lane;
      int d = idx2 >> 3, s4c = idx2 & 7;
      f32x4 vv = *(const f32x4*)(ep + d * 36 + s4c * 4);
      *(f32x4*)(out + outbase + (size_t)(dt * 32 + d) * 4096 + s4c * 4) = vv;
    }
  }
}

// ---------------------------------------------------------------------------
extern "C" void kernel_launch(void* const* d_in, const int* in_sizes, int n_in,
                              void* d_out, int out_size, void* d_ws, size_t ws_size,
                              hipStream_t stream) {
  const float* x = (const float*)d_in[0];
  const float* wdw = (const float*)d_in[1];
  const float* wpw = (const float*)d_in[2];
  float* out = (float*)d_out;
  char* ws = (char*)d_ws;
  unsigned short* dwt = (unsigned short*)(ws + OFF_DW);
  unsigned short* wbf = (unsigned short*)(ws + OFF_WB);
  unsigned short* q = (unsigned short*)(ws + OFF_Q);
  unsigned short* k = (unsigned short*)(ws + OFF_K);
  unsigned short* v = (unsigned short*)(ws + OFF_V);

  k_wcvt<<<dim3(768), dim3(256), 0, stream>>>(wpw, wbf);
  k_dw<<<dim3(64, 4, 4), dim3(256), 0, stream>>>(x, wdw, dwt);
  k_pw<<<dim3(64, 4), dim3(256), 0, stream>>>(dwt, wbf, q, k, v);
  k_attn<<<dim3(256), dim3(512), 0, stream>>>(q, k, v, out);
}